// Round 3
// baseline (344.632 us; speedup 1.0000x reference)
//
#include <hip/hip_runtime.h>

#define N_NODES 50000
#define N_EDGES 800000
#define D_IN 128
#define D_HID 512
#define D_OUT 128

#define EH_FLOAT4 (N_EDGES * (D_IN / 4))      // 25,600,000 float4
#define CPB 4096                              // float4 per copy chunk (64 KB)

// copy chunk quotas (sum * CPB == EH_FLOAT4 exactly: 6250 chunks)
#define C_PREP 400
#define C_HIST 450
#define C_SCAN 200
#define C_FILL 450
#define C_GATH 2600
#define C_GEMMF 2150

typedef __attribute__((ext_vector_type(8))) short short8v;
typedef __attribute__((ext_vector_type(4))) float f32x4;

__device__ __forceinline__ unsigned short f2bf(float f) {
    union { float f; unsigned u; } v; v.f = f;
    unsigned u = v.u;
    return (unsigned short)((u + 0x7FFFu + ((u >> 16) & 1u)) >> 16);
}
__device__ __forceinline__ float bf2f(unsigned u16) {
    union { unsigned u; float f; } v; v.u = u16 << 16;
    return v.f;
}

// Bresenham interleave: for block b of T=W+C total, return copy-index if copy
// block else -1, and work-index via *w.
__device__ __forceinline__ long long interleave(long long b, long long C,
                                                long long T, long long* w) {
    long long cb = (C == 0) ? 0 : (b * C) / T;
    bool isCopy = C != 0 && ((b + 1) * C) / T > cb;
    *w = b - cb;
    return isCopy ? cb : -1;
}

// 64KB copy chunk — R3: plain cached loads/stores (NT ablation)
__device__ __forceinline__ void copy_chunk(const float4* __restrict__ src,
                                           float4* __restrict__ dst,
                                           long long base, long long cb) {
    const f32x4* s = (const f32x4*)src;
    f32x4* d = (f32x4*)dst;
    long long o = base + cb * CPB + threadIdx.x;
#pragma unroll
    for (int i = 0; i < 16; ++i) {
        d[o + i * 256] = s[o + i * 256];
    }
}

// ---------------- fused prep: cvt nh, cvt W1->W1T, cvt W2->W2T, zero counts+flags ----------------
__global__ __launch_bounds__(256) void k_prep(const float4* __restrict__ nh,
                                              const float* __restrict__ W1,
                                              const float* __restrict__ W2,
                                              uint2* __restrict__ nh16,
                                              unsigned short* __restrict__ W1T,
                                              unsigned short* __restrict__ W2T,
                                              int* __restrict__ counts,
                                              int* __restrict__ pub,
                                              const float4* __restrict__ csrc,
                                              float4* __restrict__ cdst,
                                              long long copyBase, int copyC) {
    long long w;
    const int W = 6250 + 256 + 256 + 196;
    long long cb = interleave(blockIdx.x, copyC, W + copyC, &w);
    if (cb >= 0) { copy_chunk(csrc, cdst, copyBase, cb); return; }
    int tid = threadIdx.x;
    if (w < 6250) {
        int i = (int)w * 256 + tid;
        if (i < N_NODES * (D_IN / 4)) {
            float4 a = nh[i];
            uint2 r;
            r.x = (unsigned)f2bf(a.x) | ((unsigned)f2bf(a.y) << 16);
            r.y = (unsigned)f2bf(a.z) | ((unsigned)f2bf(a.w) << 16);
            nh16[i] = r;
        }
    } else if (w < 6506) {
        int i = (int)(w - 6250) * 256 + tid;          // W1T[512][128]
        int n = i >> 7, k = i & 127;
        W1T[i] = f2bf(W1[k * D_HID + n]);
    } else if (w < 6762) {
        int i = (int)(w - 6506) * 256 + tid;          // W2T[128][512]
        int n = i >> 9, k = i & 511;
        W2T[i] = f2bf(W2[k * D_OUT + n]);
    } else {
        int i = (int)(w - 6762) * 256 + tid;
        if (i <= N_NODES) counts[i] = 0;
        if (i < 196) pub[i] = 0;                      // lookback flags
    }
}

// ---------------- CSR build ----------------

__global__ __launch_bounds__(256) void k_hist(const int* __restrict__ ei,
                                              int* __restrict__ counts,
                                              const float4* __restrict__ csrc,
                                              float4* __restrict__ cdst,
                                              long long copyBase, int copyC) {
    long long w;
    const int W = (N_EDGES + 255) / 256;
    long long cb = interleave(blockIdx.x, copyC, W + copyC, &w);
    if (cb >= 0) { copy_chunk(csrc, cdst, copyBase, cb); return; }
    int e = (int)w * 256 + threadIdx.x;
    if (e >= N_EDGES) return;
    atomicAdd(&counts[ei[N_EDGES + e]], 1);
}

// single-kernel exclusive scan via decoupled lookback.
__global__ __launch_bounds__(256) void k_scan_lb(const int* __restrict__ counts,
                                                 int* __restrict__ offs,
                                                 int* __restrict__ cursors,
                                                 int* __restrict__ pub,
                                                 const float4* __restrict__ csrc,
                                                 float4* __restrict__ cdst,
                                                 long long copyBase, int copyC) {
    long long w;
    long long cb = interleave(blockIdx.x, copyC, 196 + copyC, &w);
    if (cb >= 0) { copy_chunk(csrc, cdst, copyBase, cb); return; }
    int b = (int)w;                                   // 0..195
    __shared__ int s[256];
    __shared__ int r[256];
    int tid = threadIdx.x;
    int i = b * 256 + tid;
    int v = (i < N_NODES) ? counts[i] : 0;
    s[tid] = v;
    __syncthreads();
#pragma unroll
    for (int off = 1; off < 256; off <<= 1) {         // inclusive scan in smem
        int t = (tid >= off) ? s[tid - off] : 0;
        __syncthreads();
        if (tid >= off) s[tid] += t;
        __syncthreads();
    }
    if (tid == 255)                                   // publish segment total (+1 tag)
        __hip_atomic_store(&pub[b], s[255] + 1, __ATOMIC_RELEASE,
                           __HIP_MEMORY_SCOPE_AGENT);
    int contrib = 0;                                  // thread tid polls predecessor tid
    if (tid < b) {
        int p;
        do {
            p = __hip_atomic_load(&pub[tid], __ATOMIC_ACQUIRE,
                                  __HIP_MEMORY_SCOPE_AGENT);
        } while (p == 0);
        contrib = p - 1;
    }
    r[tid] = contrib;
    __syncthreads();
#pragma unroll
    for (int off = 128; off > 0; off >>= 1) {         // block reduce -> r[0]
        if (tid < off) r[tid] += r[tid + off];
        __syncthreads();
    }
    int prefix = r[0];
    if (i < N_NODES) {
        int o = (s[tid] - v) + prefix;                // exclusive + carry-in
        offs[i] = o;
        cursors[i] = o;
    }
    if (b == 0 && tid == 0) offs[N_NODES] = N_EDGES;
}

__global__ __launch_bounds__(256) void k_fill(const int* __restrict__ ei,
                                              int* __restrict__ cursors,
                                              int* __restrict__ csr_src,
                                              const float4* __restrict__ csrc,
                                              float4* __restrict__ cdst,
                                              long long copyBase, int copyC) {
    long long w;
    const int W = (N_EDGES + 255) / 256;
    long long cb = interleave(blockIdx.x, copyC, W + copyC, &w);
    if (cb >= 0) { copy_chunk(csrc, cdst, copyBase, cb); return; }
    int e = (int)w * 256 + threadIdx.x;
    if (e >= N_EDGES) return;
    int dst = ei[N_EDGES + e];
    int pos = atomicAdd(&cursors[dst], 1);
    csr_src[pos] = ei[e];
}

// one wave per node: acc16[n] = bf16((1+eps)*nh[n] + sum nh[src])
__global__ __launch_bounds__(256) void k_gather16(const unsigned* __restrict__ nh16,
                                                  const int* __restrict__ csr_src,
                                                  const int* __restrict__ offs,
                                                  const float* __restrict__ eps,
                                                  unsigned* __restrict__ acc16,
                                                  const float4* __restrict__ csrc,
                                                  float4* __restrict__ cdst,
                                                  long long copyBase, int copyC) {
    long long w;
    const int W = (N_NODES + 3) / 4;
    long long cb = interleave(blockIdx.x, copyC, W + copyC, &w);
    if (cb >= 0) { copy_chunk(csrc, cdst, copyBase, cb); return; }
    int node = (int)w * 4 + (threadIdx.x >> 6);
    if (node >= N_NODES) return;
    int lane = threadIdx.x & 63;
    int beg = offs[node], end = offs[node + 1];
    float sx = 0.f, sy = 0.f;
    int j = beg;
    for (; j + 1 < end; j += 2) {
        unsigned v0 = nh16[(size_t)csr_src[j] * 64 + lane];
        unsigned v1 = nh16[(size_t)csr_src[j + 1] * 64 + lane];
        sx += bf2f(v0 & 0xFFFFu) + bf2f(v1 & 0xFFFFu);
        sy += bf2f(v0 >> 16) + bf2f(v1 >> 16);
    }
    if (j < end) {
        unsigned v0 = nh16[(size_t)csr_src[j] * 64 + lane];
        sx += bf2f(v0 & 0xFFFFu);
        sy += bf2f(v0 >> 16);
    }
    float sc = 1.0f + eps[0];
    unsigned m = nh16[(size_t)node * 64 + lane];
    sx += sc * bf2f(m & 0xFFFFu);
    sy += sc * bf2f(m >> 16);
    acc16[(size_t)node * 64 + lane] =
        (unsigned)f2bf(sx) | ((unsigned)f2bf(sy) << 16);
}

__global__ __launch_bounds__(256) void k_copy_eh(const float4* __restrict__ src,
                                                 float4* __restrict__ dst) {
    int i = blockIdx.x * 256 + threadIdx.x;
    if (i >= EH_FLOAT4) return;
    dst[i] = src[i];
}

// ---------------- fused MLP: out = relu(A*W1+b1)*W2+b2, H never leaves LDS ----------------
__global__ __launch_bounds__(256, 2) void gemm_fused(
        const unsigned short* __restrict__ A,     // [M][128] bf16 (acc16)
        const unsigned short* __restrict__ W1t,   // [512][128] bf16
        const float* __restrict__ b1,
        const unsigned short* __restrict__ W2t,   // [128][512] bf16
        const float* __restrict__ b2,
        float* __restrict__ Cout,                 // [M][128] f32
        int M,
        const float4* __restrict__ csrc, float4* __restrict__ cdst,
        long long copyBase, int copyC, int workW) {
    long long w;
    long long cb = interleave(blockIdx.x, copyC, workW + copyC, &w);
    if (cb >= 0) { copy_chunk(csrc, cdst, copyBase, cb); return; }

    __shared__ unsigned short As[128][40];
    __shared__ unsigned short Bs[128][40];
    __shared__ unsigned short Hs[128][136];

    const int tid = threadIdx.x;
    const int m0 = (int)w * 128;
    const int wid = tid >> 6;
    const int lane = tid & 63;
    const int wr = wid >> 1;
    const int wc = wid & 1;
    const int l15 = lane & 15;
    const int kg = lane >> 4;

    f32x4 acc2[4][4];
#pragma unroll
    for (int i = 0; i < 4; ++i)
#pragma unroll
        for (int j = 0; j < 4; ++j) acc2[i][j] = (f32x4){0.f, 0.f, 0.f, 0.f};

    for (int ht = 0; ht < 4; ++ht) {
        // ---------- phase 1: H-tile = relu(A * W1T[ht] + b1) ----------
        f32x4 acc1[4][4];
#pragma unroll
        for (int i = 0; i < 4; ++i)
#pragma unroll
            for (int j = 0; j < 4; ++j) acc1[i][j] = (f32x4){0.f, 0.f, 0.f, 0.f};

        for (int ks = 0; ks < 4; ++ks) {              // K1 = 128
#pragma unroll
            for (int p = 0; p < 2; ++p) {
                int t = tid + p * 256;
                int row = t >> 2;
                int cg = t & 3;
                float4 va = make_float4(0.f, 0.f, 0.f, 0.f);
                int gr = m0 + row;
                if (gr < M)
                    va = *(const float4*)(A + (size_t)gr * D_IN + ks * 32 + cg * 8);
                *(float4*)&As[row][cg * 8] = va;
                float4 vb = *(const float4*)(W1t + (size_t)(ht * 128 + row) * D_IN
                                             + ks * 32 + cg * 8);
                *(float4*)&Bs[row][cg * 8] = vb;
            }
            __syncthreads();
            short8v a[4], bb[4];
#pragma unroll
            for (int i = 0; i < 4; ++i)
                a[i] = *(const short8v*)&As[wr * 64 + i * 16 + l15][kg * 8];
#pragma unroll
            for (int j = 0; j < 4; ++j)
                bb[j] = *(const short8v*)&Bs[wc * 64 + j * 16 + l15][kg * 8];
#pragma unroll
            for (int i = 0; i < 4; ++i)
#pragma unroll
                for (int j = 0; j < 4; ++j)
                    acc1[i][j] = __builtin_amdgcn_mfma_f32_16x16x32_bf16(
                        a[i], bb[j], acc1[i][j], 0, 0, 0);
            __syncthreads();
        }

        // bias + relu -> bf16 into Hs (C/D layout: col = l15 group, row = kg*4+q)
#pragma unroll
        for (int j = 0; j < 4; ++j) {
            int lc = wc * 64 + j * 16 + l15;
            float bv = b1[ht * 128 + lc];
#pragma unroll
            for (int i = 0; i < 4; ++i)
#pragma unroll
                for (int q = 0; q < 4; ++q) {
                    float v = acc1[i][j][q] + bv;
                    Hs[wr * 64 + i * 16 + kg * 4 + q][lc] = f2bf(fmaxf(v, 0.f));
                }
        }
        __syncthreads();

        // ---------- phase 2: acc2 += Hs * W2T[:, ht*128 .. +128] ----------
#pragma unroll
        for (int ks = 0; ks < 4; ++ks) {
            short8v a[4], bb[4];
#pragma unroll
            for (int i = 0; i < 4; ++i)
                a[i] = *(const short8v*)&Hs[wr * 64 + i * 16 + l15][ks * 32 + kg * 8];
#pragma unroll
            for (int j = 0; j < 4; ++j)
                bb[j] = *(const short8v*)(W2t + (size_t)(wc * 64 + j * 16 + l15) * D_HID
                                          + ht * 128 + ks * 32 + kg * 8);
#pragma unroll
            for (int i = 0; i < 4; ++i)
#pragma unroll
                for (int j = 0; j < 4; ++j)
                    acc2[i][j] = __builtin_amdgcn_mfma_f32_16x16x32_bf16(
                        a[i], bb[j], acc2[i][j], 0, 0, 0);
        }
        __syncthreads();   // Hs/As/Bs reused next ht
    }

    // ---------- epilogue: out f32 ----------
#pragma unroll
    for (int j = 0; j < 4; ++j) {
        int gc = wc * 64 + j * 16 + l15;
        float bv = b2[gc];
#pragma unroll
        for (int i = 0; i < 4; ++i) {
#pragma unroll
            for (int q = 0; q < 4; ++q) {
                int gr = m0 + wr * 64 + i * 16 + kg * 4 + q;
                if (gr >= M) continue;
                Cout[(size_t)gr * D_OUT + gc] = acc2[i][j][q] + bv;
            }
        }
    }
}

extern "C" void kernel_launch(void* const* d_in, const int* in_sizes, int n_in,
                              void* d_out, int out_size, void* d_ws, size_t ws_size,
                              hipStream_t stream) {
    const float* nh  = (const float*)d_in[0];
    const float* eh  = (const float*)d_in[1];
    const float* W1  = (const float*)d_in[2];
    const float* b1  = (const float*)d_in[3];
    const float* W2  = (const float*)d_in[4];
    const float* b2  = (const float*)d_in[5];
    const float* eps = (const float*)d_in[6];
    const int*   ei  = (const int*)d_in[7];

    float* out0 = (float*)d_out;
    float* out1 = out0 + (size_t)N_NODES * D_OUT;   // [N_EDGES, D_IN], 409.6 MB

    const size_t NEED = 36u << 20;
    bool useWs = (d_ws != nullptr) && (ws_size >= NEED);
    char* base = useWs ? (char*)d_ws : (char*)out1;

    unsigned*       nh16  = (unsigned*)(base);                      // 12.8 MB
    unsigned*       acc16 = (unsigned*)(base + (13u << 20));        // 12.8 MB
    unsigned short* w1t   = (unsigned short*)(base + (26u << 20));  // 128 KB
    unsigned short* w2t   = (unsigned short*)(base + (27u << 20));  // 128 KB
    int*            ibase = (int*)(base + (28u << 20));
    int* offs    = ibase;             // 50001
    int* cursors = ibase + 65536;     // 50000 (counts)
    int* pub     = ibase + 131072;    // 196 lookback flags
    int* csr_src = ibase + 262144;    // 800000

    const float4* csrc = (const float4*)eh;
    float4*       cdst = (float4*)out1;

    int c0 = useWs ? C_PREP  : 0;  long long b0 = 0;
    int c1 = useWs ? C_HIST  : 0;  long long b1c = (long long)(C_PREP) * CPB;
    int c2 = useWs ? C_SCAN  : 0;  long long b2c = (long long)(C_PREP + C_HIST) * CPB;
    int c3 = useWs ? C_FILL  : 0;  long long b3c = (long long)(C_PREP + C_HIST + C_SCAN) * CPB;
    int c4 = useWs ? C_GATH  : 0;  long long b4c = (long long)(C_PREP + C_HIST + C_SCAN + C_FILL) * CPB;
    int c5 = useWs ? C_GEMMF : 0;  long long b5c = (long long)(C_PREP + C_HIST + C_SCAN + C_FILL + C_GATH) * CPB;

    k_prep<<<6958 + c0, 256, 0, stream>>>((const float4*)nh, W1, W2,
        (uint2*)nh16, w1t, w2t, cursors, pub, csrc, cdst, b0, c0);

    k_hist<<<3125 + c1, 256, 0, stream>>>(ei, cursors, csrc, cdst, b1c, c1);
    k_scan_lb<<<196 + c2, 256, 0, stream>>>(cursors, offs, cursors, pub,
                                            csrc, cdst, b2c, c2);
    k_fill<<<3125 + c3, 256, 0, stream>>>(ei, cursors, csr_src, csrc, cdst, b3c, c3);
    k_gather16<<<12500 + c4, 256, 0, stream>>>(nh16, csr_src, offs, eps, acc16,
                                               csrc, cdst, b4c, c4);

    const int WFblocks = (N_NODES + 127) / 128;     // 391
    gemm_fused<<<WFblocks + c5, 256, 0, stream>>>(
        (const unsigned short*)acc16, w1t, b1, w2t, b2, out0,
        N_NODES, csrc, cdst, b5c, c5, WFblocks);

    if (!useWs) {
        k_copy_eh<<<(EH_FLOAT4 + 255) / 256, 256, 0, stream>>>(csrc, cdst);
    }
}

// Round 4
// 299.375 us; speedup vs baseline: 1.1512x; 1.1512x over previous
//
#include <hip/hip_runtime.h>

#define N_NODES 50000
#define N_EDGES 800000
#define D_IN 128
#define D_HID 512
#define D_OUT 128

#define EH_FLOAT4 (N_EDGES * (D_IN / 4))      // 25,600,000 float4
#define CPB 4096                              // float4 per copy chunk (64 KB)

// copy chunk quotas (sum * CPB == EH_FLOAT4 exactly: 6250 chunks)
// R4: NT reverted; gemm work shrunk so 600 chunks moved gemm->hist/fill
#define C_PREP 400
#define C_HIST 750
#define C_SCAN 200
#define C_FILL 750
#define C_GATH 2600
#define C_GEMMF 1550

typedef __attribute__((ext_vector_type(8))) short short8v;
typedef __attribute__((ext_vector_type(4))) float f32x4;

__device__ __forceinline__ unsigned short f2bf(float f) {
    union { float f; unsigned u; } v; v.f = f;
    unsigned u = v.u;
    return (unsigned short)((u + 0x7FFFu + ((u >> 16) & 1u)) >> 16);
}
__device__ __forceinline__ float bf2f(unsigned u16) {
    union { unsigned u; float f; } v; v.u = u16 << 16;
    return v.f;
}

// Bresenham interleave: for block b of T=W+C total, return copy-index if copy
// block else -1, and work-index via *w.
__device__ __forceinline__ long long interleave(long long b, long long C,
                                                long long T, long long* w) {
    long long cb = (C == 0) ? 0 : (b * C) / T;
    bool isCopy = C != 0 && ((b + 1) * C) / T > cb;
    *w = b - cb;
    return isCopy ? cb : -1;
}

// non-temporal 64KB copy chunk (NT proven better: R3 ablation +24us without it)
__device__ __forceinline__ void copy_chunk(const float4* __restrict__ src,
                                           float4* __restrict__ dst,
                                           long long base, long long cb) {
    const f32x4* s = (const f32x4*)src;
    f32x4* d = (f32x4*)dst;
    long long o = base + cb * CPB + threadIdx.x;
#pragma unroll
    for (int i = 0; i < 16; ++i) {
        f32x4 v = __builtin_nontemporal_load(&s[o + i * 256]);
        __builtin_nontemporal_store(v, &d[o + i * 256]);
    }
}

// ---------------- fused prep: cvt nh, cvt W1->W1T, cvt W2->W2T, zero counts+flags ----------------
__global__ __launch_bounds__(256) void k_prep(const float4* __restrict__ nh,
                                              const float* __restrict__ W1,
                                              const float* __restrict__ W2,
                                              uint2* __restrict__ nh16,
                                              unsigned short* __restrict__ W1T,
                                              unsigned short* __restrict__ W2T,
                                              int* __restrict__ counts,
                                              int* __restrict__ pub,
                                              const float4* __restrict__ csrc,
                                              float4* __restrict__ cdst,
                                              long long copyBase, int copyC) {
    long long w;
    const int W = 6250 + 256 + 256 + 196;
    long long cb = interleave(blockIdx.x, copyC, W + copyC, &w);
    if (cb >= 0) { copy_chunk(csrc, cdst, copyBase, cb); return; }
    int tid = threadIdx.x;
    if (w < 6250) {
        int i = (int)w * 256 + tid;
        if (i < N_NODES * (D_IN / 4)) {
            float4 a = nh[i];
            uint2 r;
            r.x = (unsigned)f2bf(a.x) | ((unsigned)f2bf(a.y) << 16);
            r.y = (unsigned)f2bf(a.z) | ((unsigned)f2bf(a.w) << 16);
            nh16[i] = r;
        }
    } else if (w < 6506) {
        int i = (int)(w - 6250) * 256 + tid;          // W1T[512][128]
        int n = i >> 7, k = i & 127;
        W1T[i] = f2bf(W1[k * D_HID + n]);
    } else if (w < 6762) {
        int i = (int)(w - 6506) * 256 + tid;          // W2T[128][512]
        int n = i >> 9, k = i & 511;
        W2T[i] = f2bf(W2[k * D_OUT + n]);
    } else {
        int i = (int)(w - 6762) * 256 + tid;
        if (i <= N_NODES) counts[i] = 0;
        if (i < 196) pub[i] = 0;                      // lookback flags
    }
}

// ---------------- CSR build ----------------

__global__ __launch_bounds__(256) void k_hist(const int* __restrict__ ei,
                                              int* __restrict__ counts,
                                              const float4* __restrict__ csrc,
                                              float4* __restrict__ cdst,
                                              long long copyBase, int copyC) {
    long long w;
    const int W = (N_EDGES + 255) / 256;
    long long cb = interleave(blockIdx.x, copyC, W + copyC, &w);
    if (cb >= 0) { copy_chunk(csrc, cdst, copyBase, cb); return; }
    int e = (int)w * 256 + threadIdx.x;
    if (e >= N_EDGES) return;
    atomicAdd(&counts[ei[N_EDGES + e]], 1);
}

// single-kernel exclusive scan via decoupled lookback.
__global__ __launch_bounds__(256) void k_scan_lb(const int* __restrict__ counts,
                                                 int* __restrict__ offs,
                                                 int* __restrict__ cursors,
                                                 int* __restrict__ pub,
                                                 const float4* __restrict__ csrc,
                                                 float4* __restrict__ cdst,
                                                 long long copyBase, int copyC) {
    long long w;
    long long cb = interleave(blockIdx.x, copyC, 196 + copyC, &w);
    if (cb >= 0) { copy_chunk(csrc, cdst, copyBase, cb); return; }
    int b = (int)w;                                   // 0..195
    __shared__ int s[256];
    __shared__ int r[256];
    int tid = threadIdx.x;
    int i = b * 256 + tid;
    int v = (i < N_NODES) ? counts[i] : 0;
    s[tid] = v;
    __syncthreads();
#pragma unroll
    for (int off = 1; off < 256; off <<= 1) {         // inclusive scan in smem
        int t = (tid >= off) ? s[tid - off] : 0;
        __syncthreads();
        if (tid >= off) s[tid] += t;
        __syncthreads();
    }
    if (tid == 255)                                   // publish segment total (+1 tag)
        __hip_atomic_store(&pub[b], s[255] + 1, __ATOMIC_RELEASE,
                           __HIP_MEMORY_SCOPE_AGENT);
    int contrib = 0;                                  // thread tid polls predecessor tid
    if (tid < b) {
        int p;
        do {
            p = __hip_atomic_load(&pub[tid], __ATOMIC_ACQUIRE,
                                  __HIP_MEMORY_SCOPE_AGENT);
        } while (p == 0);
        contrib = p - 1;
    }
    r[tid] = contrib;
    __syncthreads();
#pragma unroll
    for (int off = 128; off > 0; off >>= 1) {         // block reduce -> r[0]
        if (tid < off) r[tid] += r[tid + off];
        __syncthreads();
    }
    int prefix = r[0];
    if (i < N_NODES) {
        int o = (s[tid] - v) + prefix;                // exclusive + carry-in
        offs[i] = o;
        cursors[i] = o;
    }
    if (b == 0 && tid == 0) offs[N_NODES] = N_EDGES;
}

__global__ __launch_bounds__(256) void k_fill(const int* __restrict__ ei,
                                              int* __restrict__ cursors,
                                              int* __restrict__ csr_src,
                                              const float4* __restrict__ csrc,
                                              float4* __restrict__ cdst,
                                              long long copyBase, int copyC) {
    long long w;
    const int W = (N_EDGES + 255) / 256;
    long long cb = interleave(blockIdx.x, copyC, W + copyC, &w);
    if (cb >= 0) { copy_chunk(csrc, cdst, copyBase, cb); return; }
    int e = (int)w * 256 + threadIdx.x;
    if (e >= N_EDGES) return;
    int dst = ei[N_EDGES + e];
    int pos = atomicAdd(&cursors[dst], 1);
    csr_src[pos] = ei[e];
}

// one wave per node: acc16[n] = bf16((1+eps)*nh[n] + sum nh[src])
// R4: 4-deep ILP (4 independent idx loads, then 4 independent row loads)
__global__ __launch_bounds__(256) void k_gather16(const unsigned* __restrict__ nh16,
                                                  const int* __restrict__ csr_src,
                                                  const int* __restrict__ offs,
                                                  const float* __restrict__ eps,
                                                  unsigned* __restrict__ acc16,
                                                  const float4* __restrict__ csrc,
                                                  float4* __restrict__ cdst,
                                                  long long copyBase, int copyC) {
    long long w;
    const int W = (N_NODES + 3) / 4;
    long long cb = interleave(blockIdx.x, copyC, W + copyC, &w);
    if (cb >= 0) { copy_chunk(csrc, cdst, copyBase, cb); return; }
    int node = (int)w * 4 + (threadIdx.x >> 6);
    if (node >= N_NODES) return;
    int lane = threadIdx.x & 63;
    int beg = offs[node], end = offs[node + 1];
    float sx = 0.f, sy = 0.f;
    int j = beg;
    for (; j + 3 < end; j += 4) {
        int s0 = csr_src[j];
        int s1 = csr_src[j + 1];
        int s2 = csr_src[j + 2];
        int s3 = csr_src[j + 3];
        unsigned v0 = nh16[(size_t)s0 * 64 + lane];
        unsigned v1 = nh16[(size_t)s1 * 64 + lane];
        unsigned v2 = nh16[(size_t)s2 * 64 + lane];
        unsigned v3 = nh16[(size_t)s3 * 64 + lane];
        sx += bf2f(v0 & 0xFFFFu) + bf2f(v1 & 0xFFFFu) +
              bf2f(v2 & 0xFFFFu) + bf2f(v3 & 0xFFFFu);
        sy += bf2f(v0 >> 16) + bf2f(v1 >> 16) + bf2f(v2 >> 16) + bf2f(v3 >> 16);
    }
    for (; j < end; ++j) {
        unsigned v0 = nh16[(size_t)csr_src[j] * 64 + lane];
        sx += bf2f(v0 & 0xFFFFu);
        sy += bf2f(v0 >> 16);
    }
    float sc = 1.0f + eps[0];
    unsigned m = nh16[(size_t)node * 64 + lane];
    sx += sc * bf2f(m & 0xFFFFu);
    sy += sc * bf2f(m >> 16);
    acc16[(size_t)node * 64 + lane] =
        (unsigned)f2bf(sx) | ((unsigned)f2bf(sy) << 16);
}

__global__ __launch_bounds__(256) void k_copy_eh(const float4* __restrict__ src,
                                                 float4* __restrict__ dst) {
    int i = blockIdx.x * 256 + threadIdx.x;
    if (i >= EH_FLOAT4) return;
    const f32x4* s = (const f32x4*)src;
    f32x4* d = (f32x4*)dst;
    f32x4 v = __builtin_nontemporal_load(&s[i]);
    __builtin_nontemporal_store(v, &d[i]);
}

// ---------------- fused MLP v2: out = relu(A*W1+b1)*W2+b2 ----------------
// R4 restructure:
//   - A-tile fragments loaded ONCE into registers (af[4][4], 64 VGPR), reused
//     for all 4 hidden tiles (was: re-staged to LDS 16x).
//   - W1t/W2t B-fragments read directly from global (256 KB total, L2-hot
//     after first block per XCD) -- no Bs staging, no staging barriers.
//   - LDS = Hs only (34.8 KB -> 2 blocks/CU with VGPR~190).
//   - 8 barriers total (was 41).
// Phase-1 computes per output-column-block j with a transient 4-frag
// accumulator (keeps VGPR under the (256,2) budget).
__global__ __launch_bounds__(256, 2) void gemm_fused(
        const unsigned short* __restrict__ A,     // [M][128] bf16 (acc16)
        const unsigned short* __restrict__ W1t,   // [512][128] bf16
        const float* __restrict__ b1,
        const unsigned short* __restrict__ W2t,   // [128][512] bf16
        const float* __restrict__ b2,
        float* __restrict__ Cout,                 // [M][128] f32
        int M,
        const float4* __restrict__ csrc, float4* __restrict__ cdst,
        long long copyBase, int copyC, int workW) {
    long long w;
    long long cb = interleave(blockIdx.x, copyC, workW + copyC, &w);
    if (cb >= 0) { copy_chunk(csrc, cdst, copyBase, cb); return; }

    __shared__ unsigned short Hs[128][136];   // stride 272B: 2-way bank alias (free)

    const int tid = threadIdx.x;
    const int m0 = (int)w * 128;
    const int wid = tid >> 6;
    const int lane = tid & 63;
    const int wr = wid >> 1;
    const int wc = wid & 1;
    const int l15 = lane & 15;
    const int kg = lane >> 4;

    // A fragments: af[ks][i] = A[m0 + wr*64 + i*16 + l15][ks*32 + kg*8 .. +8)
    short8v af[4][4];
#pragma unroll
    for (int i = 0; i < 4; ++i) {
        int gr = m0 + wr * 64 + i * 16 + l15;
        const unsigned short* Ar = A + (size_t)gr * D_IN + kg * 8;
        if (gr < M) {
#pragma unroll
            for (int ks = 0; ks < 4; ++ks)
                af[ks][i] = *(const short8v*)(Ar + ks * 32);
        } else {
#pragma unroll
            for (int ks = 0; ks < 4; ++ks)
                af[ks][i] = (short8v){0, 0, 0, 0, 0, 0, 0, 0};
        }
    }

    f32x4 acc2[4][4];
#pragma unroll
    for (int i = 0; i < 4; ++i)
#pragma unroll
        for (int j = 0; j < 4; ++j) acc2[i][j] = (f32x4){0.f, 0.f, 0.f, 0.f};

    for (int ht = 0; ht < 4; ++ht) {
        __syncthreads();   // prior phase-2 Hs reads complete before overwrite

        // ---------- phase 1: Hs = relu(A * W1T[ht] + b1), per column-block j ----------
#pragma unroll
        for (int j = 0; j < 4; ++j) {
            const int lc = wc * 64 + j * 16 + l15;
            const unsigned short* Wr = W1t + (size_t)(ht * 128 + lc) * D_IN + kg * 8;
            f32x4 a1[4];
#pragma unroll
            for (int i = 0; i < 4; ++i) a1[i] = (f32x4){0.f, 0.f, 0.f, 0.f};
#pragma unroll
            for (int ks = 0; ks < 4; ++ks) {
                short8v bbj = *(const short8v*)(Wr + ks * 32);
#pragma unroll
                for (int i = 0; i < 4; ++i)
                    a1[i] = __builtin_amdgcn_mfma_f32_16x16x32_bf16(
                        af[ks][i], bbj, a1[i], 0, 0, 0);
            }
            float bv = b1[ht * 128 + lc];
#pragma unroll
            for (int i = 0; i < 4; ++i)
#pragma unroll
                for (int q = 0; q < 4; ++q) {
                    float v = a1[i][q] + bv;
                    Hs[wr * 64 + i * 16 + kg * 4 + q][lc] = f2bf(fmaxf(v, 0.f));
                }
        }
        __syncthreads();   // Hs tile complete

        // ---------- phase 2: acc2 += Hs * W2T[:, ht*128 .. +128] ----------
#pragma unroll
        for (int ks = 0; ks < 4; ++ks) {
            short8v ha[4], bb[4];
#pragma unroll
            for (int i = 0; i < 4; ++i)
                ha[i] = *(const short8v*)&Hs[wr * 64 + i * 16 + l15][ks * 32 + kg * 8];
#pragma unroll
            for (int j = 0; j < 4; ++j)
                bb[j] = *(const short8v*)(W2t + (size_t)(wc * 64 + j * 16 + l15) * D_HID
                                          + ht * 128 + ks * 32 + kg * 8);
#pragma unroll
            for (int i = 0; i < 4; ++i)
#pragma unroll
                for (int j = 0; j < 4; ++j)
                    acc2[i][j] = __builtin_amdgcn_mfma_f32_16x16x32_bf16(
                        ha[i], bb[j], acc2[i][j], 0, 0, 0);
        }
    }

    // ---------- epilogue: out f32 ----------
#pragma unroll
    for (int j = 0; j < 4; ++j) {
        int gc = wc * 64 + j * 16 + l15;
        float bv = b2[gc];
#pragma unroll
        for (int i = 0; i < 4; ++i) {
#pragma unroll
            for (int q = 0; q < 4; ++q) {
                int gr = m0 + wr * 64 + i * 16 + kg * 4 + q;
                if (gr >= M) continue;
                Cout[(size_t)gr * D_OUT + gc] = acc2[i][j][q] + bv;
            }
        }
    }
}

extern "C" void kernel_launch(void* const* d_in, const int* in_sizes, int n_in,
                              void* d_out, int out_size, void* d_ws, size_t ws_size,
                              hipStream_t stream) {
    const float* nh  = (const float*)d_in[0];
    const float* eh  = (const float*)d_in[1];
    const float* W1  = (const float*)d_in[2];
    const float* b1  = (const float*)d_in[3];
    const float* W2  = (const float*)d_in[4];
    const float* b2  = (const float*)d_in[5];
    const float* eps = (const float*)d_in[6];
    const int*   ei  = (const int*)d_in[7];

    float* out0 = (float*)d_out;
    float* out1 = out0 + (size_t)N_NODES * D_OUT;   // [N_EDGES, D_IN], 409.6 MB

    const size_t NEED = 36u << 20;
    bool useWs = (d_ws != nullptr) && (ws_size >= NEED);
    char* base = useWs ? (char*)d_ws : (char*)out1;

    unsigned*       nh16  = (unsigned*)(base);                      // 12.8 MB
    unsigned*       acc16 = (unsigned*)(base + (13u << 20));        // 12.8 MB
    unsigned short* w1t   = (unsigned short*)(base + (26u << 20));  // 128 KB
    unsigned short* w2t   = (unsigned short*)(base + (27u << 20));  // 128 KB
    int*            ibase = (int*)(base + (28u << 20));
    int* offs    = ibase;             // 50001
    int* cursors = ibase + 65536;     // 50000 (counts)
    int* pub     = ibase + 131072;    // 196 lookback flags
    int* csr_src = ibase + 262144;    // 800000

    const float4* csrc = (const float4*)eh;
    float4*       cdst = (float4*)out1;

    int c0 = useWs ? C_PREP  : 0;  long long b0 = 0;
    int c1 = useWs ? C_HIST  : 0;  long long b1c = (long long)(C_PREP) * CPB;
    int c2 = useWs ? C_SCAN  : 0;  long long b2c = (long long)(C_PREP + C_HIST) * CPB;
    int c3 = useWs ? C_FILL  : 0;  long long b3c = (long long)(C_PREP + C_HIST + C_SCAN) * CPB;
    int c4 = useWs ? C_GATH  : 0;  long long b4c = (long long)(C_PREP + C_HIST + C_SCAN + C_FILL) * CPB;
    int c5 = useWs ? C_GEMMF : 0;  long long b5c = (long long)(C_PREP + C_HIST + C_SCAN + C_FILL + C_GATH) * CPB;

    k_prep<<<6958 + c0, 256, 0, stream>>>((const float4*)nh, W1, W2,
        (uint2*)nh16, w1t, w2t, cursors, pub, csrc, cdst, b0, c0);

    k_hist<<<3125 + c1, 256, 0, stream>>>(ei, cursors, csrc, cdst, b1c, c1);
    k_scan_lb<<<196 + c2, 256, 0, stream>>>(cursors, offs, cursors, pub,
                                            csrc, cdst, b2c, c2);
    k_fill<<<3125 + c3, 256, 0, stream>>>(ei, cursors, csr_src, csrc, cdst, b3c, c3);
    k_gather16<<<12500 + c4, 256, 0, stream>>>(nh16, csr_src, offs, eps, acc16,
                                               csrc, cdst, b4c, c4);

    const int WFblocks = (N_NODES + 127) / 128;     // 391
    gemm_fused<<<WFblocks + c5, 256, 0, stream>>>(
        (const unsigned short*)acc16, w1t, b1, w2t, b2, out0,
        N_NODES, csrc, cdst, b5c, c5, WFblocks);

    if (!useWs) {
        k_copy_eh<<<(EH_FLOAT4 + 255) / 256, 256, 0, stream>>>(csrc, cdst);
    }
}